// Round 2
// baseline (1760.434 us; speedup 1.0000x reference)
//
#include <hip/hip_runtime.h>
#include <hip/hip_bf16.h>
#include <stdint.h>

typedef __bf16 bf16;
typedef __bf16 bfrag __attribute__((ext_vector_type(8)));
typedef short s16x8 __attribute__((ext_vector_type(8)));
typedef float f32x4 __attribute__((ext_vector_type(4)));
typedef float f32x16 __attribute__((ext_vector_type(16)));

#define DEV __device__ __forceinline__

DEV bfrag ldg16(const bf16* p){ return *(const bfrag*)p; }   // 16B-aligned load

struct U64x2 { uint64_t a, b; };
DEV bfrag ld2x8(const bf16* p){                               // two 8B loads (8B-aligned)
  U64x2 t; t.a = *(const uint64_t*)p; t.b = *(const uint64_t*)(p+4);
  return __builtin_bit_cast(bfrag, t);
}

DEV f32x4  mfma16(bfrag a, bfrag b, f32x4  c){ return __builtin_amdgcn_mfma_f32_16x16x32_bf16(a,b,c,0,0,0); }
DEV f32x16 mfma32(bfrag a, bfrag b, f32x16 c){ return __builtin_amdgcn_mfma_f32_32x32x16_bf16(a,b,c,0,0,0); }

DEV f32x16 zero16(){
  f32x16 v;
  for(int i=0;i<16;++i) v[i]=0.f;
  return v;
}
DEV f32x4 zero4(){
  f32x4 v;
  for(int i=0;i<4;++i) v[i]=0.f;
  return v;
}

DEV float sigm(float x){ return 1.0f/(1.0f+__expf(-x)); }

// ---------------------------------------------------------------- k_prep
// Reorders/converts all weights to bf16 layouts; builds LSTM aux tables; h0->hcur.
__global__ __launch_bounds__(256) void k_prep(
    const float* __restrict__ c1w, const float* __restrict__ c2w,
    const float* __restrict__ c3w, const float* __restrict__ fcw,
    const float* __restrict__ Wih, const float* __restrict__ WhhF,
    const float* __restrict__ bih, const float* __restrict__ bhh,
    const float* __restrict__ aw1, const float* __restrict__ aw2,
    const float* __restrict__ vw1, const float* __restrict__ vw2,
    const float* __restrict__ h0,
    bf16* w1b, bf16* w2r, bf16* w3r, bf16* fcwr, bf16* Wx, bf16* Whh,
    float* biasL, float* Wr, float* Wa, bf16* advw1, bf16* valw1,
    bf16* w2advP, bf16* w2valP, bf16* hcur)
{
  long i = (long)blockIdx.x*256 + threadIdx.x;
  if (i < 2048){ int co=(int)(i>>6), k=(int)(i&63);
    w1b[i] = (bf16)(c1w[co*64+k]*(1.f/255.f)); return; } i -= 2048;
  if (i < 32768){ int o=(int)(i>>9), k=(int)(i&511);
    int ky=k>>7, kx=(k>>5)&3, ci=k&31;
    w2r[i] = (bf16)c2w[((o*32+ci)*4+ky)*4+kx]; return; } i -= 32768;
  if (i < 36864){ int o=(int)(i/576), k=(int)(i%576);
    int ky=k/192, rem=k-ky*192, kx=rem>>6, ci=rem&63;
    w3r[i] = (bf16)c3w[((o*64+ci)*3+ky)*3+kx]; return; } i -= 36864;
  if (i < 1638400){ int o=(int)(i/3200), k=(int)(i%3200);
    float v = 0.f;
    if (k < 3136){ int y=k/448, rem=k-y*448, x=rem>>6, ci=rem&63;
      v = fcw[o*3136 + ci*49 + y*7 + x]; }
    fcwr[i] = (bf16)v; return; } i -= 1638400;
  if (i < 1048576){ int n=(int)(i>>9), k=(int)(i&511);
    Wx[i] = (bf16)Wih[n*531+k]; return; } i -= 1048576;
  if (i < 1048576){ int n=(int)(i>>9), k=(int)(i&511);
    Whh[i] = (bf16)WhhF[n*512+k]; return; } i -= 1048576;
  if (i < 2048){ biasL[i] = bih[i]+bhh[i]; return; } i -= 2048;
  if (i < 2048){ Wr[i] = Wih[i*531+512]; return; } i -= 2048;
  if (i < 36864){ int j=(int)(i>>11), n=(int)(i&2047);
    Wa[i] = Wih[n*531+513+j]; return; } i -= 36864;
  if (i < 262144){ advw1[i] = (bf16)aw1[i]; return; } i -= 262144;
  if (i < 262144){ valw1[i] = (bf16)vw1[i]; return; } i -= 262144;
  if (i < 65536){ int n=(int)(i>>9), k=(int)(i&511);
    w2advP[i] = (bf16)(n<18 ? aw2[n*512+k] : 0.f); return; } i -= 65536;
  if (i < 65536){ int n=(int)(i>>9), k=(int)(i&511);
    w2valP[i] = (bf16)(n==0 ? vw2[k] : 0.f); return; } i -= 65536;
  if (i < 32768){ hcur[i] = (bf16)h0[i]; return; }
}

// ---------------------------------------------------------------- conv1 (MFMA, im2col from LDS)
// per block: 4 images (1/wave). M=400 px (13 tiles of 32, clamped), N=32, K=64.
__global__ __launch_bounds__(256,2) void k_conv1(
    const int* __restrict__ o, const bf16* __restrict__ w1b,
    const float* __restrict__ c1b, bf16* __restrict__ act1)
{
  __shared__ bf16 simg[4][7056];
  const int tid = threadIdx.x;
  const long imgbase = (long)blockIdx.x*4;
  const int4* src = (const int4*)o;
  for (int u = tid; u < 7056; u += 256){
    int4 v = src[imgbase*1764 + u];
    int il = u/1764, p4 = u - il*1764;
    uint32_t lo = (uint32_t)__builtin_bit_cast(uint16_t,(bf16)(float)v.x)
                | ((uint32_t)__builtin_bit_cast(uint16_t,(bf16)(float)v.y)<<16);
    uint32_t hi = (uint32_t)__builtin_bit_cast(uint16_t,(bf16)(float)v.z)
                | ((uint32_t)__builtin_bit_cast(uint16_t,(bf16)(float)v.w)<<16);
    *(uint64_t*)&simg[il][p4*4] = (uint64_t)lo | ((uint64_t)hi<<32);
  }
  __syncthreads();
  const int w = tid>>6, l = tid&63;
  const bf16* sp = &simg[w][0];
  bfrag bw[4];
  #pragma unroll
  for (int ks=0;ks<4;++ks) bw[ks] = ldg16(w1b + (l&31)*64 + ks*16 + 8*(l>>5));
  const float bias = c1b[l&31];
  for (int mt=0; mt<13; ++mt){
    f32x16 acc = zero16();
    int m0 = mt*32 + (l&31);
    int p  = m0>399 ? 399 : m0;
    int oy = p/20, ox = p - oy*20;
    #pragma unroll
    for (int ks=0;ks<4;++ks){
      int ky = 2*ks + (l>>5);
      bfrag a = ld2x8(sp + (oy*4+ky)*84 + ox*4);
      acc = mfma32(a, bw[ks], acc);
    }
    #pragma unroll
    for (int r2=0;r2<16;++r2){
      int row = (r2&3) + 8*(r2>>2) + 4*(l>>5);
      int m = mt*32 + row;
      if (m < 400){
        float v = acc[r2] + bias; v = v>0.f ? v : 0.f;
        act1[(imgbase+w)*12800 + m*32 + (l&31)] = (bf16)v;
      }
    }
  }
}

// ---------------------------------------------------------------- conv2 (MFMA, A+B from global/L1)
// per wave: 1 image. M=81(->96), N=64, K=512 (k = ky*128+kx*32+ci)
__global__ __launch_bounds__(256,2) void k_conv2(
    const bf16* __restrict__ act1, const bf16* __restrict__ w2r,
    const float* __restrict__ c2b, bf16* __restrict__ act2)
{
  const int tid=threadIdx.x, w=tid>>6, l=tid&63;
  const long img = (long)blockIdx.x*4 + w;
  const bf16* A = act1 + img*12800;
  f32x16 acc[3][2];
  #pragma unroll
  for(int a2=0;a2<3;++a2){ acc[a2][0]=zero16(); acc[a2][1]=zero16(); }
  #pragma unroll 4
  for (int ks=0; ks<32; ++ks){
    int k  = ks*16 + 8*(l>>5);
    int ky = k>>7, kx = (k>>5)&3, ci = k&31;
    bfrag b0 = ldg16(w2r + (l&31)*512 + k);
    bfrag b1 = ldg16(w2r + (32+(l&31))*512 + k);
    #pragma unroll
    for (int mt=0; mt<3; ++mt){
      int m = mt*32 + (l&31); int p = m>80 ? 80 : m;
      int oy = p/9, ox = p - oy*9;
      bfrag a = ldg16(A + ((oy*2+ky)*20 + (ox*2+kx))*32 + ci);
      acc[mt][0] = mfma32(a, b0, acc[mt][0]);
      acc[mt][1] = mfma32(a, b1, acc[mt][1]);
    }
  }
  const float bias0 = c2b[l&31], bias1 = c2b[32+(l&31)];
  #pragma unroll
  for (int mt=0; mt<3; ++mt){
    #pragma unroll
    for (int r2=0;r2<16;++r2){
      int row = (r2&3) + 8*(r2>>2) + 4*(l>>5);
      int m = mt*32 + row;
      if (m < 81){
        float v0 = acc[mt][0][r2] + bias0; v0 = v0>0.f ? v0 : 0.f;
        float v1 = acc[mt][1][r2] + bias1; v1 = v1>0.f ? v1 : 0.f;
        act2[img*5184 + m*64 + (l&31)]      = (bf16)v0;
        act2[img*5184 + m*64 + 32 + (l&31)] = (bf16)v1;
      }
    }
  }
}

// ---------------------------------------------------------------- conv3
// per wave: 1 image. M=49(->64), N=64, K=576 (k = ky*192+kx*64+ci). out row stride 3200 (padded)
__global__ __launch_bounds__(256,2) void k_conv3(
    const bf16* __restrict__ act2, const bf16* __restrict__ w3r,
    const float* __restrict__ c3b, bf16* __restrict__ act3)
{
  const int tid=threadIdx.x, w=tid>>6, l=tid&63;
  const long img = (long)blockIdx.x*4 + w;
  const bf16* A = act2 + img*5184;
  f32x16 acc[2][2];
  #pragma unroll
  for(int a2=0;a2<2;++a2){ acc[a2][0]=zero16(); acc[a2][1]=zero16(); }
  #pragma unroll 4
  for (int ks=0; ks<36; ++ks){
    int k  = ks*16 + 8*(l>>5);
    int ky = k/192, rem = k - ky*192, kx = rem>>6, ci = rem&63;
    bfrag b0 = ldg16(w3r + (l&31)*576 + k);
    bfrag b1 = ldg16(w3r + (32+(l&31))*576 + k);
    #pragma unroll
    for (int mt=0; mt<2; ++mt){
      int m = mt*32 + (l&31); int p = m>48 ? 48 : m;
      int oy = p/7, ox = p - oy*7;
      bfrag a = ldg16(A + ((oy+ky)*9 + (ox+kx))*64 + ci);
      acc[mt][0] = mfma32(a, b0, acc[mt][0]);
      acc[mt][1] = mfma32(a, b1, acc[mt][1]);
    }
  }
  const float bias0 = c3b[l&31], bias1 = c3b[32+(l&31)];
  #pragma unroll
  for (int mt=0; mt<2; ++mt){
    #pragma unroll
    for (int r2=0;r2<16;++r2){
      int row = (r2&3) + 8*(r2>>2) + 4*(l>>5);
      int m = mt*32 + row;
      if (m < 49){
        float v0 = acc[mt][0][r2] + bias0; v0 = v0>0.f ? v0 : 0.f;
        float v1 = acc[mt][1][r2] + bias1; v1 = v1>0.f ? v1 : 0.f;
        act3[img*3200 + m*64 + (l&31)]      = (bf16)v0;
        act3[img*3200 + m*64 + 32 + (l&31)] = (bf16)v1;
      }
    }
  }
}

// ---------------------------------------------------------------- generic GEMM: C = act(A @ W^T + bias)
// A[M,K] bf16 (lda), W[N,K] bf16 (ldb). Block tile 64x128, 4 waves, K multiple of 128.
template<bool RELU, bool OUTBF16>
__global__ __launch_bounds__(256,4) void k_gemm(
    const bf16* __restrict__ A, long lda,
    const bf16* __restrict__ W, long ldb,
    const float* __restrict__ bias,
    float* __restrict__ outF, bf16* __restrict__ outB, long ldo, int K)
{
  __shared__ bf16 sA[8192];   // 64 rows x 128 k, XOR-swizzled
  char* sb = (char*)sA;
  const int tid=threadIdx.x, w=tid>>6, l=tid&63;
  const int m0 = blockIdx.x*64, n0 = blockIdx.y*128;
  f32x16 acc[2]; acc[0]=zero16(); acc[1]=zero16();
  const int mt = w&1;
  const int rowa = mt*32 + (l&31);
  for (int kc=0; kc<K; kc+=128){
    __syncthreads();
    for (int u = tid; u < 1024; u += 256){
      int row = u>>4, seg = u&15;
      s16x8 v = *(const s16x8*)(A + (long)(m0+row)*lda + kc + seg*8);
      *(s16x8*)(sb + row*256 + ((seg*16) ^ ((row&15)<<4))) = v;
    }
    __syncthreads();
    #pragma unroll
    for (int ks=0; ks<8; ++ks){
      bfrag a = *(const bfrag*)(sb + rowa*256 + ((ks*32 + (l>>5)*16) ^ ((rowa&15)<<4)));
      #pragma unroll
      for (int j=0;j<2;++j){
        int nt = (w>>1)*2 + j;
        bfrag b = ldg16(W + (long)(n0 + nt*32 + (l&31))*ldb + kc + ks*16 + 8*(l>>5));
        acc[j] = mfma32(a, b, acc[j]);
      }
    }
  }
  #pragma unroll
  for (int j=0;j<2;++j){
    int nt = (w>>1)*2 + j;
    int gc = n0 + nt*32 + (l&31);
    float bv = bias ? bias[gc] : 0.f;
    #pragma unroll
    for (int r2=0;r2<16;++r2){
      int row = (r2&3) + 8*(r2>>2) + 4*(l>>5);
      long gr = m0 + mt*32 + row;
      float v = acc[j][r2] + bv;
      if (RELU) v = v>0.f ? v : 0.f;
      if (OUTBF16) outB[gr*ldo + gc] = (bf16)v;
      else         outF[gr*ldo + gc] = v;
    }
  }
}

// ---------------------------------------------------------------- G fixup: += r*Wr[n] + Wa[a][n]
__global__ __launch_bounds__(256) void k_fixupG(
    float* __restrict__ G, const float* __restrict__ rr,
    const int* __restrict__ act, const float* __restrict__ Wr,
    const float* __restrict__ Wa)
{
  long i = (long)blockIdx.x*256 + threadIdx.x;   // 5120*2048 exactly
  int tb = (int)(i>>11); int n = (int)(i&2047);
  G[i] += rr[tb]*Wr[n] + Wa[(long)act[tb]*2048 + n];
}

// ---------------------------------------------------------------- LSTM recurrence
DEV void group_barrier(unsigned* cnt, unsigned* gen){
  __syncthreads();
  if (threadIdx.x == 0){
    __threadfence();
    unsigned g = __hip_atomic_load(gen, __ATOMIC_RELAXED, __HIP_MEMORY_SCOPE_AGENT);
    unsigned arr = __hip_atomic_fetch_add(cnt, 1u, __ATOMIC_ACQ_REL, __HIP_MEMORY_SCOPE_AGENT);
    if (arr == 15u){
      __hip_atomic_store(cnt, 0u, __ATOMIC_RELAXED, __HIP_MEMORY_SCOPE_AGENT);
      __hip_atomic_store(gen, g+1u, __ATOMIC_RELEASE, __HIP_MEMORY_SCOPE_AGENT);
    } else {
      while (__hip_atomic_load(gen, __ATOMIC_ACQUIRE, __HIP_MEMORY_SCOPE_AGENT) == g)
        __builtin_amdgcn_s_sleep(1);
    }
    __threadfence();
  }
  __syncthreads();
}

// 64 blocks: 4 groups x 16. Block owns 32 hidden units for 16 batch rows.
// W_hh fragments held in registers for all 80 steps. h exchanged via double-buffered hcur.
__global__ __launch_bounds__(256,1) void k_lstm(
    const float* __restrict__ G, const int* __restrict__ done,
    const float* __restrict__ c0, const bf16* __restrict__ Whh,
    bf16* __restrict__ hcur, bf16* __restrict__ hseq,
    float* __restrict__ outH, float* __restrict__ outC,
    unsigned* __restrict__ bar)
{
  __shared__ bf16 sh[8192];          // 16 x 512 bf16, swizzled
  __shared__ float sg[4][16][32];    // gates
  __shared__ float sc[16][32];       // cell state
  const int tid=threadIdx.x, w=tid>>6, l=tid&63;
  const int blk=blockIdx.x, grp=blk>>4, jj=blk&15;
  const int bb = grp*16, uu = jj*32;
  unsigned* cnt = bar + grp*16;
  unsigned* gen = bar + grp*16 + 8;

  for (int p=tid; p<512; p+=256){ int m=p>>5, u=p&31; sc[m][u] = c0[(bb+m)*512 + uu + u]; }

  bfrag wb0[16], wb1[16];
  {
    const long row0 = (long)w*512 + uu + (l&15);
    #pragma unroll
    for (int ks=0; ks<16; ++ks){
      int k = ks*32 + 8*(l>>4);
      wb0[ks] = ldg16(Whh + row0*512 + k);
      wb1[ks] = ldg16(Whh + (row0+16)*512 + k);
    }
  }
  char* shb = (char*)sh;
  for (int t=0; t<80; ++t){
    const bf16* hin  = hcur + (t&1)*32768;
    bf16*       hout = hcur + ((t+1)&1)*32768;
    // stage masked h for this group's 16 batch rows
    for (int u2=tid; u2<1024; u2+=256){
      int row = u2>>6, seg = u2&63;
      s16x8 v = *(const s16x8*)(hin + (bb+row)*512 + seg*8);
      if (done[t*64 + bb + row]){ s16x8 z = {0,0,0,0,0,0,0,0}; v = z; }
      *(s16x8*)(shb + row*1024 + ((seg*16) ^ (row<<4))) = v;
    }
    __syncthreads();
    // prefetch x-part of gates
    float gv0[4], gv1[4];
    const float* Gt = G + ((long)t*64 + bb)*2048 + w*512 + uu;
    #pragma unroll
    for (int r2=0;r2<4;++r2){
      int m = (l>>4)*4 + r2;
      gv0[r2] = Gt[(long)m*2048 + (l&15)];
      gv1[r2] = Gt[(long)m*2048 + 16 + (l&15)];
    }
    f32x4 a0 = zero4(), a1 = zero4();
    {
      const int row = l&15;
      #pragma unroll
      for (int ks=0; ks<16; ++ks){
        bfrag a = *(const bfrag*)(shb + row*1024 + ((ks*64 + (l>>4)*16) ^ (row<<4)));
        a0 = mfma16(a, wb0[ks], a0);
        a1 = mfma16(a, wb1[ks], a1);
      }
    }
    #pragma unroll
    for (int r2=0;r2<4;++r2){
      int m = (l>>4)*4 + r2;
      sg[w][m][(l&15)]      = a0[r2] + gv0[r2];
      sg[w][m][16+(l&15)]   = a1[r2] + gv1[r2];
    }
    __syncthreads();
    {
      int p0 = tid*2; int m = p0>>5, u = p0&31;
      int dn = done[t*64 + bb + m];
      float c_0 = dn ? 0.f : sc[m][u];
      float c_1 = dn ? 0.f : sc[m][u+1];
      float i0=sg[0][m][u],   f0=sg[1][m][u],   g0=sg[2][m][u],   o0=sg[3][m][u];
      float i1=sg[0][m][u+1], f1=sg[1][m][u+1], g1=sg[2][m][u+1], o1=sg[3][m][u+1];
      float cn0 = sigm(f0)*c_0 + sigm(i0)*tanhf(g0);
      float cn1 = sigm(f1)*c_1 + sigm(i1)*tanhf(g1);
      float h_0 = sigm(o0)*tanhf(cn0);
      float h_1 = sigm(o1)*tanhf(cn1);
      sc[m][u] = cn0; sc[m][u+1] = cn1;
      uint32_t pk = (uint32_t)__builtin_bit_cast(uint16_t,(bf16)h_0)
                  | ((uint32_t)__builtin_bit_cast(uint16_t,(bf16)h_1)<<16);
      *(uint32_t*)(hout + (bb+m)*512 + uu + u) = pk;
      *(uint32_t*)(hseq + ((long)t*64 + bb + m)*512 + uu + u) = pk;
      if (t == 79){
        outH[(bb+m)*512 + uu + u]   = h_0;  outH[(bb+m)*512 + uu + u+1] = h_1;
        outC[(bb+m)*512 + uu + u]   = cn0;  outC[(bb+m)*512 + uu + u+1] = cn1;
      }
    }
    if (t < 79) group_barrier(cnt, gen);
  }
}

// ---------------------------------------------------------------- final q
__global__ __launch_bounds__(256) void k_qfinal(
    const float* __restrict__ advP, const float* __restrict__ valP,
    const float* __restrict__ ab2, const float* __restrict__ vb2,
    float* __restrict__ q)
{
  int s = blockIdx.x*256 + threadIdx.x;   // 5120
  float av[18]; float sum = 0.f;
  #pragma unroll
  for (int j=0;j<18;++j){ av[j] = advP[(long)s*128 + j] + ab2[j]; sum += av[j]; }
  float val = valP[(long)s*128] + vb2[0];
  float mean = sum * (1.f/18.f);
  #pragma unroll
  for (int j=0;j<18;++j) q[(long)s*18 + j] = val + av[j] - mean;
}

// ================================================================ host
extern "C" void kernel_launch(void* const* d_in, const int* in_sizes, int n_in,
                              void* d_out, int out_size, void* d_ws, size_t ws_size,
                              hipStream_t stream)
{
  (void)in_sizes; (void)n_in; (void)out_size;
  const int*   o_in = (const int*)  d_in[0];
  const int*   a_in = (const int*)  d_in[1];
  const float* r_in = (const float*)d_in[2];
  const int*   done = (const int*)  d_in[3];
  const float* h0   = (const float*)d_in[4];
  const float* c0   = (const float*)d_in[5];
  const float* c1w  = (const float*)d_in[6],  *c1b=(const float*)d_in[7];
  const float* c2w  = (const float*)d_in[8],  *c2b=(const float*)d_in[9];
  const float* c3w  = (const float*)d_in[10], *c3b=(const float*)d_in[11];
  const float* fcw  = (const float*)d_in[12], *fcb=(const float*)d_in[13];
  const float* Wih  = (const float*)d_in[14], *WhhF=(const float*)d_in[15];
  const float* bih  = (const float*)d_in[16], *bhh=(const float*)d_in[17];
  const float* aw1  = (const float*)d_in[18], *ab1=(const float*)d_in[19];
  const float* aw2  = (const float*)d_in[20], *ab2=(const float*)d_in[21];
  const float* vw1  = (const float*)d_in[22], *vb1=(const float*)d_in[23];
  const float* vw2  = (const float*)d_in[24], *vb2=(const float*)d_in[25];

  char* ws = (char*)d_ws;
  size_t off = 0;
  auto alloc = [&](size_t b){ size_t p = off; off = (off + b + 255) & ~(size_t)255; return p; };
  bf16*  act1   = (bf16*) (ws + alloc(32768000));      // 1280 x 400 x 32
  bf16*  act2   = (bf16*) (ws + alloc(13271040));      // 1280 x 81 x 64
  bf16*  act3   = (bf16*) (ws + alloc(8192000));       // 1280 x 3200 (padded)
  bf16*  hidden = (bf16*) (ws + alloc(5242880));       // 5120 x 512
  float* G      = (float*)(ws + alloc(41943040));      // 5120 x 2048
  bf16*  hseq   = (bf16*) (ws + alloc(5242880));       // 5120 x 512
  bf16*  za     = (bf16*) (ws + alloc(5242880));
  bf16*  zv     = (bf16*) (ws + alloc(5242880));
  float* advP   = (float*)(ws + alloc(2621440));       // 5120 x 128
  float* valP   = (float*)(ws + alloc(2621440));
  bf16*  hcur   = (bf16*) (ws + alloc(131072));        // 2 x 64 x 512 (double buffered)
  bf16*  w1b    = (bf16*) (ws + alloc(4096));
  bf16*  w2r    = (bf16*) (ws + alloc(65536));
  bf16*  w3r    = (bf16*) (ws + alloc(73728));
  bf16*  fcwr   = (bf16*) (ws + alloc(3276800));       // 512 x 3200
  bf16*  Wx     = (bf16*) (ws + alloc(2097152));
  bf16*  Whh    = (bf16*) (ws + alloc(2097152));
  float* biasL  = (float*)(ws + alloc(8192));
  float* Wr     = (float*)(ws + alloc(8192));
  float* Wa     = (float*)(ws + alloc(147456));
  bf16*  advw1  = (bf16*) (ws + alloc(524288));
  bf16*  valw1  = (bf16*) (ws + alloc(524288));
  bf16*  w2advP = (bf16*) (ws + alloc(131072));
  bf16*  w2valP = (bf16*) (ws + alloc(131072));
  unsigned* bar = (unsigned*)(ws + alloc(256));
  if (off > ws_size) return;  // workspace too small; nothing sane we can do

  float* qout = (float*)d_out;
  float* outH = qout + 92160;
  float* outC = qout + 124928;

  (void)hipMemsetAsync(bar, 0, 256, stream);
  (void)hipMemsetAsync(act3, 0, 8192000, stream);

  k_prep<<<17720, 256, 0, stream>>>(c1w, c2w, c3w, fcw, Wih, WhhF, bih, bhh,
      aw1, aw2, vw1, vw2, h0, w1b, w2r, w3r, fcwr, Wx, Whh,
      biasL, Wr, Wa, advw1, valw1, w2advP, w2valP, hcur);

  for (int ch = 0; ch < 4; ++ch){
    const int* o_ch = o_in + (long)ch*1280*7056;
    k_conv1<<<320, 256, 0, stream>>>(o_ch, w1b, c1b, act1);
    k_conv2<<<320, 256, 0, stream>>>(act1, w2r, c2b, act2);
    k_conv3<<<320, 256, 0, stream>>>(act2, w3r, c3b, act3);
    // FC: [1280,3200] @ [512,3200]^T -> hidden (bf16, relu)
    k_gemm<true,true><<<dim3(20,4), 256, 0, stream>>>(
        act3, 3200, fcwr, 3200, fcb, nullptr, hidden + (long)ch*1280*512, 512, 3200);
  }
  // G = hidden @ Wx^T + (b_ih+b_hh)
  k_gemm<false,false><<<dim3(80,16), 256, 0, stream>>>(
      hidden, 512, Wx, 512, biasL, G, nullptr, 2048, 512);
  k_fixupG<<<40960, 256, 0, stream>>>(G, r_in, a_in, Wr, Wa);

  k_lstm<<<64, 256, 0, stream>>>(G, done, c0, Whh, hcur, hseq, outH, outC, bar);

  // heads
  k_gemm<true,true><<<dim3(80,4), 256, 0, stream>>>(
      hseq, 512, advw1, 512, ab1, nullptr, za, 512, 512);
  k_gemm<true,true><<<dim3(80,4), 256, 0, stream>>>(
      hseq, 512, valw1, 512, vb1, nullptr, zv, 512, 512);
  k_gemm<false,false><<<dim3(80,1), 256, 0, stream>>>(
      za, 512, w2advP, 512, nullptr, advP, nullptr, 128, 512);
  k_gemm<false,false><<<dim3(80,1), 256, 0, stream>>>(
      zv, 512, w2valP, 512, nullptr, valP, nullptr, 128, 512);
  k_qfinal<<<20, 256, 0, stream>>>(advP, valP, ab2, vb2, qout);
}

// Round 3
// 1319.314 us; speedup vs baseline: 1.3344x; 1.3344x over previous
//
#include <hip/hip_runtime.h>
#include <hip/hip_bf16.h>
#include <stdint.h>

typedef __bf16 bf16;
typedef __bf16 bfrag __attribute__((ext_vector_type(8)));
typedef short s16x8 __attribute__((ext_vector_type(8)));
typedef float f32x4 __attribute__((ext_vector_type(4)));
typedef float f32x16 __attribute__((ext_vector_type(16)));

#define DEV __device__ __forceinline__

DEV bfrag ldg16(const bf16* p){ return *(const bfrag*)p; }   // 16B-aligned load

struct U64x2 { uint64_t a, b; };
DEV bfrag ld2x8(const bf16* p){                               // two 8B loads (8B-aligned)
  U64x2 t; t.a = *(const uint64_t*)p; t.b = *(const uint64_t*)(p+4);
  return __builtin_bit_cast(bfrag, t);
}

DEV f32x4  mfma16(bfrag a, bfrag b, f32x4  c){ return __builtin_amdgcn_mfma_f32_16x16x32_bf16(a,b,c,0,0,0); }
DEV f32x16 mfma32(bfrag a, bfrag b, f32x16 c){ return __builtin_amdgcn_mfma_f32_32x32x16_bf16(a,b,c,0,0,0); }

DEV f32x16 zero16(){
  f32x16 v;
  for(int i=0;i<16;++i) v[i]=0.f;
  return v;
}
DEV f32x4 zero4(){
  f32x4 v;
  for(int i=0;i<4;++i) v[i]=0.f;
  return v;
}

DEV float sigm(float x){ return 1.0f/(1.0f+__expf(-x)); }

// ---------------------------------------------------------------- k_prep
__global__ __launch_bounds__(256) void k_prep(
    const float* __restrict__ c1w, const float* __restrict__ c2w,
    const float* __restrict__ c3w, const float* __restrict__ fcw,
    const float* __restrict__ Wih, const float* __restrict__ WhhF,
    const float* __restrict__ bih, const float* __restrict__ bhh,
    const float* __restrict__ aw1, const float* __restrict__ aw2,
    const float* __restrict__ vw1, const float* __restrict__ vw2,
    const float* __restrict__ h0,
    bf16* w1b, bf16* w2r, bf16* w3r, bf16* fcwr, bf16* Wx, bf16* Whh,
    float* biasL, float* Wr, float* Wa, bf16* advw1, bf16* valw1,
    bf16* w2advP, bf16* w2valP, bf16* hcur)
{
  long i = (long)blockIdx.x*256 + threadIdx.x;
  if (i < 2048){ int co=(int)(i>>6), k=(int)(i&63);
    w1b[i] = (bf16)(c1w[co*64+k]*(1.f/255.f)); return; } i -= 2048;
  if (i < 32768){ int o=(int)(i>>9), k=(int)(i&511);
    int ky=k>>7, kx=(k>>5)&3, ci=k&31;
    w2r[i] = (bf16)c2w[((o*32+ci)*4+ky)*4+kx]; return; } i -= 32768;
  if (i < 36864){ int o=(int)(i/576), k=(int)(i%576);
    int ky=k/192, rem=k-ky*192, kx=rem>>6, ci=rem&63;
    w3r[i] = (bf16)c3w[((o*64+ci)*3+ky)*3+kx]; return; } i -= 36864;
  if (i < 1638400){ int o=(int)(i/3200), k=(int)(i%3200);
    float v = 0.f;
    if (k < 3136){ int y=k/448, rem=k-y*448, x=rem>>6, ci=rem&63;
      v = fcw[o*3136 + ci*49 + y*7 + x]; }
    fcwr[i] = (bf16)v; return; } i -= 1638400;
  if (i < 1048576){ int n=(int)(i>>9), k=(int)(i&511);
    Wx[i] = (bf16)Wih[n*531+k]; return; } i -= 1048576;
  if (i < 1048576){ int n=(int)(i>>9), k=(int)(i&511);
    Whh[i] = (bf16)WhhF[n*512+k]; return; } i -= 1048576;
  if (i < 2048){ biasL[i] = bih[i]+bhh[i]; return; } i -= 2048;
  if (i < 2048){ Wr[i] = Wih[i*531+512]; return; } i -= 2048;
  if (i < 36864){ int j=(int)(i>>11), n=(int)(i&2047);
    Wa[i] = Wih[n*531+513+j]; return; } i -= 36864;
  if (i < 262144){ advw1[i] = (bf16)aw1[i]; return; } i -= 262144;
  if (i < 262144){ valw1[i] = (bf16)vw1[i]; return; } i -= 262144;
  if (i < 65536){ int n=(int)(i>>9), k=(int)(i&511);
    w2advP[i] = (bf16)(n<18 ? aw2[n*512+k] : 0.f); return; } i -= 65536;
  if (i < 65536){ int n=(int)(i>>9), k=(int)(i&511);
    w2valP[i] = (bf16)(n==0 ? vw2[k] : 0.f); return; } i -= 65536;
  if (i < 32768){ hcur[i] = (bf16)h0[i]; return; }
}

// ---------------------------------------------------------------- conv1 (MFMA, im2col from LDS)
__global__ __launch_bounds__(256,2) void k_conv1(
    const int* __restrict__ o, const bf16* __restrict__ w1b,
    const float* __restrict__ c1b, bf16* __restrict__ act1)
{
  __shared__ bf16 simg[4][7056];
  const int tid = threadIdx.x;
  const long imgbase = (long)blockIdx.x*4;
  const int4* src = (const int4*)o;
  for (int u = tid; u < 7056; u += 256){
    int4 v = src[imgbase*1764 + u];
    int il = u/1764, p4 = u - il*1764;
    uint32_t lo = (uint32_t)__builtin_bit_cast(uint16_t,(bf16)(float)v.x)
                | ((uint32_t)__builtin_bit_cast(uint16_t,(bf16)(float)v.y)<<16);
    uint32_t hi = (uint32_t)__builtin_bit_cast(uint16_t,(bf16)(float)v.z)
                | ((uint32_t)__builtin_bit_cast(uint16_t,(bf16)(float)v.w)<<16);
    *(uint64_t*)&simg[il][p4*4] = (uint64_t)lo | ((uint64_t)hi<<32);
  }
  __syncthreads();
  const int w = tid>>6, l = tid&63;
  const bf16* sp = &simg[w][0];
  bfrag bw[4];
  #pragma unroll
  for (int ks=0;ks<4;++ks) bw[ks] = ldg16(w1b + (l&31)*64 + ks*16 + 8*(l>>5));
  const float bias = c1b[l&31];
  for (int mt=0; mt<13; ++mt){
    f32x16 acc = zero16();
    int m0 = mt*32 + (l&31);
    int p  = m0>399 ? 399 : m0;
    int oy = p/20, ox = p - oy*20;
    #pragma unroll
    for (int ks=0;ks<4;++ks){
      int ky = 2*ks + (l>>5);
      bfrag a = ld2x8(sp + (oy*4+ky)*84 + ox*4);
      acc = mfma32(a, bw[ks], acc);
    }
    #pragma unroll
    for (int r2=0;r2<16;++r2){
      int row = (r2&3) + 8*(r2>>2) + 4*(l>>5);
      int m = mt*32 + row;
      if (m < 400){
        float v = acc[r2] + bias; v = v>0.f ? v : 0.f;
        act1[(imgbase+w)*12800 + m*32 + (l&31)] = (bf16)v;
      }
    }
  }
}

// ---------------------------------------------------------------- conv2
__global__ __launch_bounds__(256,2) void k_conv2(
    const bf16* __restrict__ act1, const bf16* __restrict__ w2r,
    const float* __restrict__ c2b, bf16* __restrict__ act2)
{
  const int tid=threadIdx.x, w=tid>>6, l=tid&63;
  const long img = (long)blockIdx.x*4 + w;
  const bf16* A = act1 + img*12800;
  f32x16 acc[3][2];
  #pragma unroll
  for(int a2=0;a2<3;++a2){ acc[a2][0]=zero16(); acc[a2][1]=zero16(); }
  #pragma unroll 4
  for (int ks=0; ks<32; ++ks){
    int k  = ks*16 + 8*(l>>5);
    int ky = k>>7, kx = (k>>5)&3, ci = k&31;
    bfrag b0 = ldg16(w2r + (l&31)*512 + k);
    bfrag b1 = ldg16(w2r + (32+(l&31))*512 + k);
    #pragma unroll
    for (int mt=0; mt<3; ++mt){
      int m = mt*32 + (l&31); int p = m>80 ? 80 : m;
      int oy = p/9, ox = p - oy*9;
      bfrag a = ldg16(A + ((oy*2+ky)*20 + (ox*2+kx))*32 + ci);
      acc[mt][0] = mfma32(a, b0, acc[mt][0]);
      acc[mt][1] = mfma32(a, b1, acc[mt][1]);
    }
  }
  const float bias0 = c2b[l&31], bias1 = c2b[32+(l&31)];
  #pragma unroll
  for (int mt=0; mt<3; ++mt){
    #pragma unroll
    for (int r2=0;r2<16;++r2){
      int row = (r2&3) + 8*(r2>>2) + 4*(l>>5);
      int m = mt*32 + row;
      if (m < 81){
        float v0 = acc[mt][0][r2] + bias0; v0 = v0>0.f ? v0 : 0.f;
        float v1 = acc[mt][1][r2] + bias1; v1 = v1>0.f ? v1 : 0.f;
        act2[img*5184 + m*64 + (l&31)]      = (bf16)v0;
        act2[img*5184 + m*64 + 32 + (l&31)] = (bf16)v1;
      }
    }
  }
}

// ---------------------------------------------------------------- conv3
__global__ __launch_bounds__(256,2) void k_conv3(
    const bf16* __restrict__ act2, const bf16* __restrict__ w3r,
    const float* __restrict__ c3b, bf16* __restrict__ act3)
{
  const int tid=threadIdx.x, w=tid>>6, l=tid&63;
  const long img = (long)blockIdx.x*4 + w;
  const bf16* A = act2 + img*5184;
  f32x16 acc[2][2];
  #pragma unroll
  for(int a2=0;a2<2;++a2){ acc[a2][0]=zero16(); acc[a2][1]=zero16(); }
  #pragma unroll 4
  for (int ks=0; ks<36; ++ks){
    int k  = ks*16 + 8*(l>>5);
    int ky = k/192, rem = k - ky*192, kx = rem>>6, ci = rem&63;
    bfrag b0 = ldg16(w3r + (l&31)*576 + k);
    bfrag b1 = ldg16(w3r + (32+(l&31))*576 + k);
    #pragma unroll
    for (int mt=0; mt<2; ++mt){
      int m = mt*32 + (l&31); int p = m>48 ? 48 : m;
      int oy = p/7, ox = p - oy*7;
      bfrag a = ldg16(A + ((oy+ky)*9 + (ox+kx))*64 + ci);
      acc[mt][0] = mfma32(a, b0, acc[mt][0]);
      acc[mt][1] = mfma32(a, b1, acc[mt][1]);
    }
  }
  const float bias0 = c3b[l&31], bias1 = c3b[32+(l&31)];
  #pragma unroll
  for (int mt=0; mt<2; ++mt){
    #pragma unroll
    for (int r2=0;r2<16;++r2){
      int row = (r2&3) + 8*(r2>>2) + 4*(l>>5);
      int m = mt*32 + row;
      if (m < 49){
        float v0 = acc[mt][0][r2] + bias0; v0 = v0>0.f ? v0 : 0.f;
        float v1 = acc[mt][1][r2] + bias1; v1 = v1>0.f ? v1 : 0.f;
        act3[img*3200 + m*64 + (l&31)]      = (bf16)v0;
        act3[img*3200 + m*64 + 32 + (l&31)] = (bf16)v1;
      }
    }
  }
}

// ---------------------------------------------------------------- generic GEMM: C = act(A @ W^T + bias)
// Optional fused fixup (for the LSTM-x GEMM): v += fixR[gr]*fixWr[gc] + fixWa[fixA[gr]*2048+gc]
template<bool RELU, bool OUTBF16>
__global__ __launch_bounds__(256,4) void k_gemm(
    const bf16* __restrict__ A, long lda,
    const bf16* __restrict__ W, long ldb,
    const float* __restrict__ bias,
    float* __restrict__ outF, bf16* __restrict__ outB, long ldo, int K,
    const float* __restrict__ fixR, const int* __restrict__ fixA,
    const float* __restrict__ fixWr, const float* __restrict__ fixWa)
{
  __shared__ bf16 sA[8192];   // 64 rows x 128 k, XOR-swizzled
  char* sb = (char*)sA;
  const int tid=threadIdx.x, w=tid>>6, l=tid&63;
  const int m0 = blockIdx.x*64, n0 = blockIdx.y*128;
  f32x16 acc[2]; acc[0]=zero16(); acc[1]=zero16();
  const int mt = w&1;
  const int rowa = mt*32 + (l&31);
  for (int kc=0; kc<K; kc+=128){
    __syncthreads();
    for (int u = tid; u < 1024; u += 256){
      int row = u>>4, seg = u&15;
      s16x8 v = *(const s16x8*)(A + (long)(m0+row)*lda + kc + seg*8);
      *(s16x8*)(sb + row*256 + ((seg*16) ^ ((row&15)<<4))) = v;
    }
    __syncthreads();
    #pragma unroll
    for (int ks=0; ks<8; ++ks){
      bfrag a = *(const bfrag*)(sb + rowa*256 + ((ks*32 + (l>>5)*16) ^ ((rowa&15)<<4)));
      #pragma unroll
      for (int j=0;j<2;++j){
        int nt = (w>>1)*2 + j;
        bfrag b = ldg16(W + (long)(n0 + nt*32 + (l&31))*ldb + kc + ks*16 + 8*(l>>5));
        acc[j] = mfma32(a, b, acc[j]);
      }
    }
  }
  #pragma unroll
  for (int j=0;j<2;++j){
    int nt = (w>>1)*2 + j;
    int gc = n0 + nt*32 + (l&31);
    float bv = bias ? bias[gc] : 0.f;
    float wrv = fixR ? fixWr[gc] : 0.f;
    #pragma unroll
    for (int r2=0;r2<16;++r2){
      int row = (r2&3) + 8*(r2>>2) + 4*(l>>5);
      long gr = m0 + mt*32 + row;
      float v = acc[j][r2] + bv;
      if (fixR) v += fixR[gr]*wrv + fixWa[(long)fixA[gr]*2048 + gc];
      if (RELU) v = v>0.f ? v : 0.f;
      if (OUTBF16) outB[gr*ldo + gc] = (bf16)v;
      else         outF[gr*ldo + gc] = v;
    }
  }
}

// ---------------------------------------------------------------- LSTM recurrence
// 64 blocks: 4 groups x 16. Block owns 32 hidden units for 16 batch rows.
// Fence-free flag protocol: all cross-block traffic via relaxed agent-scope
// (sc1) atomics; arrival = per-block flag store after vmcnt drain; wait =
// wave-parallel poll of the 16 group flags.
__global__ __launch_bounds__(256,1) void k_lstm(
    const float* __restrict__ G, const int* __restrict__ done,
    const float* __restrict__ c0, const bf16* __restrict__ Whh,
    bf16* __restrict__ hcur, bf16* __restrict__ hseq,
    float* __restrict__ outH, float* __restrict__ outC,
    unsigned* __restrict__ bar)
{
  __shared__ bf16 sh[8192];          // 16 x 512 bf16, swizzled
  __shared__ float sg[4][16][32];    // gates
  __shared__ float sc[16][32];       // cell state
  const int tid=threadIdx.x, w=tid>>6, l=tid&63;
  const int blk=blockIdx.x, grp=blk>>4, jj=blk&15;
  const int bb = grp*16, uu = jj*32;
  unsigned* flags = bar + grp*16;

  for (int p=tid; p<512; p+=256){ int m=p>>5, u=p&31; sc[m][u] = c0[(bb+m)*512 + uu + u]; }

  bfrag wb0[16], wb1[16];
  {
    const long row0 = (long)w*512 + uu + (l&15);
    #pragma unroll
    for (int ks=0; ks<16; ++ks){
      int k = ks*32 + 8*(l>>4);
      wb0[ks] = ldg16(Whh + row0*512 + k);
      wb1[ks] = ldg16(Whh + (row0+16)*512 + k);
    }
  }
  char* shb = (char*)sh;
  for (int t=0; t<80; ++t){
    if (t > 0){
      // wait until all 16 blocks of the group have published h_t
      for (;;){
        unsigned v = __hip_atomic_load(&flags[l&15], __ATOMIC_RELAXED, __HIP_MEMORY_SCOPE_AGENT);
        if (__all((int)v >= t)) break;
        __builtin_amdgcn_s_sleep(1);
      }
    }
    const bf16* hin  = hcur + (t&1)*32768;
    bf16*       hout = hcur + ((t+1)&1)*32768;
    // stage masked h for this group's 16 batch rows (coherent 8B loads)
    #pragma unroll
    for (int u2=tid; u2<2048; u2+=256){
      int row = u2>>7, seg = u2&127;
      uint64_t v = __hip_atomic_load((const uint64_t*)(hin + ((long)(bb+row)<<9) + seg*4),
                                     __ATOMIC_RELAXED, __HIP_MEMORY_SCOPE_AGENT);
      if (done[t*64 + bb + row]) v = 0;
      *(uint64_t*)(shb + row*1024 + ((seg*8) ^ (row<<4))) = v;
    }
    __syncthreads();
    // x-part of gates (independent of h; overlaps MFMA latency)
    float gv0[4], gv1[4];
    const float* Gt = G + ((long)t*64 + bb)*2048 + w*512 + uu;
    #pragma unroll
    for (int r2=0;r2<4;++r2){
      int m = (l>>4)*4 + r2;
      gv0[r2] = Gt[(long)m*2048 + (l&15)];
      gv1[r2] = Gt[(long)m*2048 + 16 + (l&15)];
    }
    f32x4 a0 = zero4(), a1 = zero4();
    {
      const int row = l&15;
      #pragma unroll
      for (int ks=0; ks<16; ++ks){
        bfrag a = *(const bfrag*)(shb + row*1024 + ((ks*64 + (l>>4)*16) ^ (row<<4)));
        a0 = mfma16(a, wb0[ks], a0);
        a1 = mfma16(a, wb1[ks], a1);
      }
    }
    #pragma unroll
    for (int r2=0;r2<4;++r2){
      int m = (l>>4)*4 + r2;
      sg[w][m][(l&15)]      = a0[r2] + gv0[r2];
      sg[w][m][16+(l&15)]   = a1[r2] + gv1[r2];
    }
    __syncthreads();
    {
      int p0 = tid*2; int m = p0>>5, u = p0&31;
      int dn = done[t*64 + bb + m];
      float c_0 = dn ? 0.f : sc[m][u];
      float c_1 = dn ? 0.f : sc[m][u+1];
      float i0=sg[0][m][u],   f0=sg[1][m][u],   g0=sg[2][m][u],   o0=sg[3][m][u];
      float i1=sg[0][m][u+1], f1=sg[1][m][u+1], g1=sg[2][m][u+1], o1=sg[3][m][u+1];
      float cn0 = sigm(f0)*c_0 + sigm(i0)*tanhf(g0);
      float cn1 = sigm(f1)*c_1 + sigm(i1)*tanhf(g1);
      float h_0 = sigm(o0)*tanhf(cn0);
      float h_1 = sigm(o1)*tanhf(cn1);
      sc[m][u] = cn0; sc[m][u+1] = cn1;
      uint32_t pk = (uint32_t)__builtin_bit_cast(uint16_t,(bf16)h_0)
                  | ((uint32_t)__builtin_bit_cast(uint16_t,(bf16)h_1)<<16);
      __hip_atomic_store((uint32_t*)(hout + ((long)(bb+m)<<9) + uu + u), pk,
                         __ATOMIC_RELAXED, __HIP_MEMORY_SCOPE_AGENT);
      *(uint32_t*)(hseq + ((long)t*64 + bb + m)*512 + uu + u) = pk;
      if (t == 79){
        outH[(bb+m)*512 + uu + u]   = h_0;  outH[(bb+m)*512 + uu + u+1] = h_1;
        outC[(bb+m)*512 + uu + u]   = cn0;  outC[(bb+m)*512 + uu + u+1] = cn1;
      }
    }
    if (t < 79){
      asm volatile("s_waitcnt vmcnt(0)" ::: "memory");
      __syncthreads();
      if (tid == 0)
        __hip_atomic_store(&flags[jj], (unsigned)(t+1), __ATOMIC_RELAXED, __HIP_MEMORY_SCOPE_AGENT);
    }
  }
}

// ---------------------------------------------------------------- final q
__global__ __launch_bounds__(256) void k_qfinal(
    const float* __restrict__ advP, const float* __restrict__ valP,
    const float* __restrict__ ab2, const float* __restrict__ vb2,
    float* __restrict__ q)
{
  int s = blockIdx.x*256 + threadIdx.x;   // 5120
  float av[18]; float sum = 0.f;
  #pragma unroll
  for (int j=0;j<18;++j){ av[j] = advP[(long)s*128 + j] + ab2[j]; sum += av[j]; }
  float val = valP[(long)s*128] + vb2[0];
  float mean = sum * (1.f/18.f);
  #pragma unroll
  for (int j=0;j<18;++j) q[(long)s*18 + j] = val + av[j] - mean;
}

// ================================================================ host
extern "C" void kernel_launch(void* const* d_in, const int* in_sizes, int n_in,
                              void* d_out, int out_size, void* d_ws, size_t ws_size,
                              hipStream_t stream)
{
  (void)in_sizes; (void)n_in; (void)out_size;
  const int*   o_in = (const int*)  d_in[0];
  const int*   a_in = (const int*)  d_in[1];
  const float* r_in = (const float*)d_in[2];
  const int*   done = (const int*)  d_in[3];
  const float* h0   = (const float*)d_in[4];
  const float* c0   = (const float*)d_in[5];
  const float* c1w  = (const float*)d_in[6],  *c1b=(const float*)d_in[7];
  const float* c2w  = (const float*)d_in[8],  *c2b=(const float*)d_in[9];
  const float* c3w  = (const float*)d_in[10], *c3b=(const float*)d_in[11];
  const float* fcw  = (const float*)d_in[12], *fcb=(const float*)d_in[13];
  const float* Wih  = (const float*)d_in[14], *WhhF=(const float*)d_in[15];
  const float* bih  = (const float*)d_in[16], *bhh=(const float*)d_in[17];
  const float* aw1  = (const float*)d_in[18], *ab1=(const float*)d_in[19];
  const float* aw2  = (const float*)d_in[20], *ab2=(const float*)d_in[21];
  const float* vw1  = (const float*)d_in[22], *vb1=(const float*)d_in[23];
  const float* vw2  = (const float*)d_in[24], *vb2=(const float*)d_in[25];

  char* ws = (char*)d_ws;
  size_t off = 0;
  auto alloc = [&](size_t b){ size_t p = off; off = (off + b + 255) & ~(size_t)255; return p; };
  bf16*  act1   = (bf16*) (ws + alloc(32768000));      // 1280 x 400 x 32
  bf16*  act2   = (bf16*) (ws + alloc(13271040));      // 1280 x 81 x 64
  bf16*  act3   = (bf16*) (ws + alloc(8192000));       // 1280 x 3200 (padded)
  bf16*  hidden = (bf16*) (ws + alloc(5242880));       // 5120 x 512
  float* G      = (float*)(ws + alloc(41943040));      // 5120 x 2048
  bf16*  hseq   = (bf16*) (ws + alloc(5242880));       // 5120 x 512
  bf16*  za     = (bf16*) (ws + alloc(5242880));
  bf16*  zv     = (bf16*) (ws + alloc(5242880));
  float* advP   = (float*)(ws + alloc(2621440));       // 5120 x 128
  float* valP   = (float*)(ws + alloc(2621440));
  bf16*  hcur   = (bf16*) (ws + alloc(131072));        // 2 x 64 x 512 (double buffered)
  bf16*  w1b    = (bf16*) (ws + alloc(4096));
  bf16*  w2r    = (bf16*) (ws + alloc(65536));
  bf16*  w3r    = (bf16*) (ws + alloc(73728));
  bf16*  fcwr   = (bf16*) (ws + alloc(3276800));       // 512 x 3200
  bf16*  Wx     = (bf16*) (ws + alloc(2097152));
  bf16*  Whh    = (bf16*) (ws + alloc(2097152));
  float* biasL  = (float*)(ws + alloc(8192));
  float* Wr     = (float*)(ws + alloc(8192));
  float* Wa     = (float*)(ws + alloc(147456));
  bf16*  advw1  = (bf16*) (ws + alloc(524288));
  bf16*  valw1  = (bf16*) (ws + alloc(524288));
  bf16*  w2advP = (bf16*) (ws + alloc(131072));
  bf16*  w2valP = (bf16*) (ws + alloc(131072));
  unsigned* bar = (unsigned*)(ws + alloc(256));
  if (off > ws_size) return;

  float* qout = (float*)d_out;
  float* outH = qout + 92160;
  float* outC = qout + 124928;

  (void)hipMemsetAsync(bar, 0, 256, stream);
  (void)hipMemsetAsync(act3, 0, 8192000, stream);

  k_prep<<<17720, 256, 0, stream>>>(c1w, c2w, c3w, fcw, Wih, WhhF, bih, bhh,
      aw1, aw2, vw1, vw2, h0, w1b, w2r, w3r, fcwr, Wx, Whh,
      biasL, Wr, Wa, advw1, valw1, w2advP, w2valP, hcur);

  for (int ch = 0; ch < 4; ++ch){
    const int* o_ch = o_in + (long)ch*1280*7056;
    k_conv1<<<320, 256, 0, stream>>>(o_ch, w1b, c1b, act1);
    k_conv2<<<320, 256, 0, stream>>>(act1, w2r, c2b, act2);
    k_conv3<<<320, 256, 0, stream>>>(act2, w3r, c3b, act3);
    k_gemm<true,true><<<dim3(20,4), 256, 0, stream>>>(
        act3, 3200, fcwr, 3200, fcb, nullptr, hidden + (long)ch*1280*512, 512, 3200,
        nullptr, nullptr, nullptr, nullptr);
  }
  // G = hidden @ Wx^T + (b_ih+b_hh) + r*Wr + Wa[a]   (fixup fused in epilogue)
  k_gemm<false,false><<<dim3(80,16), 256, 0, stream>>>(
      hidden, 512, Wx, 512, biasL, G, nullptr, 2048, 512,
      r_in, a_in, Wr, Wa);

  k_lstm<<<64, 256, 0, stream>>>(G, done, c0, Whh, hcur, hseq, outH, outC, bar);

  // heads
  k_gemm<true,true><<<dim3(80,4), 256, 0, stream>>>(
      hseq, 512, advw1, 512, ab1, nullptr, za, 512, 512,
      nullptr, nullptr, nullptr, nullptr);
  k_gemm<true,true><<<dim3(80,4), 256, 0, stream>>>(
      hseq, 512, valw1, 512, vb1, nullptr, zv, 512, 512,
      nullptr, nullptr, nullptr, nullptr);
  k_gemm<false,false><<<dim3(80,1), 256, 0, stream>>>(
      za, 512, w2advP, 512, nullptr, advP, nullptr, 128, 512,
      nullptr, nullptr, nullptr, nullptr);
  k_gemm<false,false><<<dim3(80,1), 256, 0, stream>>>(
      zv, 512, w2valP, 512, nullptr, valP, nullptr, 128, 512,
      nullptr, nullptr, nullptr, nullptr);
  k_qfinal<<<20, 256, 0, stream>>>(advP, valP, ab2, vb2, qout);
}

// Round 4
// 763.734 us; speedup vs baseline: 2.3050x; 1.7275x over previous
//
#include <hip/hip_runtime.h>
#include <hip/hip_bf16.h>
#include <stdint.h>

typedef __bf16 bf16;
typedef __bf16 bfrag __attribute__((ext_vector_type(8)));
typedef short s16x8 __attribute__((ext_vector_type(8)));
typedef float f32x4 __attribute__((ext_vector_type(4)));
typedef float f32x16 __attribute__((ext_vector_type(16)));
typedef uint32_t u32x4 __attribute__((ext_vector_type(4)));

#define DEV __device__ __forceinline__

DEV bfrag ldg16(const bf16* p){ return *(const bfrag*)p; }

struct U64x2 { uint64_t a, b; };
DEV bfrag ld2x8(const bf16* p){
  U64x2 t; t.a = *(const uint64_t*)p; t.b = *(const uint64_t*)(p+4);
  return __builtin_bit_cast(bfrag, t);
}

DEV f32x4  mfma16(bfrag a, bfrag b, f32x4  c){ return __builtin_amdgcn_mfma_f32_16x16x32_bf16(a,b,c,0,0,0); }
DEV f32x16 mfma32(bfrag a, bfrag b, f32x16 c){ return __builtin_amdgcn_mfma_f32_32x32x16_bf16(a,b,c,0,0,0); }

DEV f32x16 zero16(){
  f32x16 v;
  for(int i=0;i<16;++i) v[i]=0.f;
  return v;
}
DEV f32x4 zero4(){
  f32x4 v;
  for(int i=0;i<4;++i) v[i]=0.f;
  return v;
}

DEV float sigm(float x){ return 1.0f/(1.0f+__expf(-x)); }

// coherent (L1+L2-bypass) 16B load — reads straight from the IF coherence point
DEV u32x4 ldcg4(const uint32_t* p){
  u32x4 r;
  asm volatile("global_load_dwordx4 %0, %1, off sc0 sc1" : "=v"(r) : "v"(p));
  return r;
}

DEV uint32_t pkbf(uint32_t a, uint32_t b){
  bf16 x = (bf16)__builtin_bit_cast(float,a), y = (bf16)__builtin_bit_cast(float,b);
  return (uint32_t)__builtin_bit_cast(uint16_t,x) | ((uint32_t)__builtin_bit_cast(uint16_t,y)<<16);
}

// ---------------------------------------------------------------- k_prep
__global__ __launch_bounds__(256) void k_prep(
    const float* __restrict__ c1w, const float* __restrict__ c2w,
    const float* __restrict__ c3w, const float* __restrict__ fcw,
    const float* __restrict__ Wih, const float* __restrict__ WhhF,
    const float* __restrict__ bih, const float* __restrict__ bhh,
    const float* __restrict__ aw1, const float* __restrict__ aw2,
    const float* __restrict__ vw1, const float* __restrict__ vw2,
    const float* __restrict__ h0,
    bf16* w1b, bf16* w2r, bf16* w3r, bf16* fcwr, bf16* Wx, bf16* Whh,
    float* biasL, float* Wr, float* Wa, bf16* headw1, float* headb1,
    bf16* w2cat, uint32_t* hcurT)
{
  long i = (long)blockIdx.x*256 + threadIdx.x;
  if (i < 2048){ int co=(int)(i>>6), k=(int)(i&63);
    w1b[i] = (bf16)(c1w[co*64+k]*(1.f/255.f)); return; } i -= 2048;
  if (i < 32768){ int o=(int)(i>>9), k=(int)(i&511);
    int ky=k>>7, kx=(k>>5)&3, ci=k&31;
    w2r[i] = (bf16)c2w[((o*32+ci)*4+ky)*4+kx]; return; } i -= 32768;
  if (i < 36864){ int o=(int)(i/576), k=(int)(i%576);
    int ky=k/192, rem=k-ky*192, kx=rem>>6, ci=rem&63;
    w3r[i] = (bf16)c3w[((o*64+ci)*3+ky)*3+kx]; return; } i -= 36864;
  if (i < 1638400){ int o=(int)(i/3200), k=(int)(i%3200);
    float v = 0.f;
    if (k < 3136){ int y=k/448, rem=k-y*448, x=rem>>6, ci=rem&63;
      v = fcw[o*3136 + ci*49 + y*7 + x]; }
    fcwr[i] = (bf16)v; return; } i -= 1638400;
  if (i < 1048576){ int n=(int)(i>>9), k=(int)(i&511);
    Wx[i] = (bf16)Wih[n*531+k]; return; } i -= 1048576;
  if (i < 1048576){ int n=(int)(i>>9), k=(int)(i&511);
    Whh[i] = (bf16)WhhF[n*512+k]; return; } i -= 1048576;
  if (i < 2048){ biasL[i] = bih[i]+bhh[i]; return; } i -= 2048;
  if (i < 2048){ Wr[i] = Wih[i*531+512]; return; } i -= 2048;
  if (i < 36864){ int j=(int)(i>>11), n=(int)(i&2047);
    Wa[i] = Wih[n*531+513+j]; return; } i -= 36864;
  if (i < 524288){ headw1[i] = (bf16)(i<262144 ? aw1[i] : vw1[i-262144]); return; } i -= 524288;
  if (i < 1024){ headb1[i] = (i<512) ? bih[0]*0.f + ((const float*)aw2)[0]*0.f + 0.f : 0.f;
    // placeholder never used — real bias below
    return; } i -= 1024;
  if (i < 32768){ int n=(int)(i>>10), k=(int)(i&1023);
    float v = 0.f;
    if (n<18 && k<512) v = aw2[n*512+k];
    else if (n==18 && k>=512) v = vw2[k-512];
    w2cat[i] = (bf16)v; return; } i -= 32768;
  if (i < 65536){
    if (i < 32768){
      uint32_t b = __builtin_bit_cast(uint32_t, h0[i]) & ~127u;  // tag 0
      hcurT[i] = b;
    } else {
      hcurT[i] = 0u;  // buf1: tag 0 (never expected at odd t)
    }
    return;
  }
}

// headb1 built separately (needs ab1/vb1 which aren't in k_prep's arg budget cleanly)
__global__ __launch_bounds__(256) void k_prep2(
    const float* __restrict__ ab1, const float* __restrict__ vb1, float* headb1)
{
  int i = blockIdx.x*256 + threadIdx.x;   // 1024
  headb1[i] = (i<512) ? ab1[i] : vb1[i-512];
}

// ---------------------------------------------------------------- conv1+conv2 fused
// 512 threads, 4 images/block, act1 lives in LDS (swizzled). 2 waves per image.
__global__ __launch_bounds__(512,1) void k_conv12(
    const int* __restrict__ o, const bf16* __restrict__ w1b,
    const float* __restrict__ c1b, const bf16* __restrict__ w2r,
    const float* __restrict__ c2b, bf16* __restrict__ act2)
{
  __shared__ bf16 simg[4][7056];     // 56448 B
  __shared__ bf16 lact[4][12800];    // 102400 B
  const int tid = threadIdx.x;
  const long imgbase = (long)blockIdx.x*4;
  const int4* src = (const int4*)o;
  for (int u = tid; u < 7056; u += 512){
    int4 v = src[imgbase*1764 + u];
    int il = u/1764, p4 = u - il*1764;
    uint32_t lo = (uint32_t)__builtin_bit_cast(uint16_t,(bf16)(float)v.x)
                | ((uint32_t)__builtin_bit_cast(uint16_t,(bf16)(float)v.y)<<16);
    uint32_t hi = (uint32_t)__builtin_bit_cast(uint16_t,(bf16)(float)v.z)
                | ((uint32_t)__builtin_bit_cast(uint16_t,(bf16)(float)v.w)<<16);
    *(uint64_t*)&simg[il][p4*4] = (uint64_t)lo | ((uint64_t)hi<<32);
  }
  __syncthreads();
  const int w = tid>>6, l = tid&63;
  const int img = w>>1, h = w&1;
  const bf16* sp = &simg[img][0];
  char* lw = (char*)&lact[img][0];
  // ---- conv1: waves of an image pair split M tiles (even/odd)
  {
    bfrag bw[4];
    #pragma unroll
    for (int ks=0;ks<4;++ks) bw[ks] = ldg16(w1b + (l&31)*64 + ks*16 + 8*(l>>5));
    const float bias = c1b[l&31];
    for (int mt=h; mt<13; mt+=2){
      f32x16 acc = zero16();
      int m0 = mt*32 + (l&31);
      int p  = m0>399 ? 399 : m0;
      int oy = p/20, ox = p - oy*20;
      #pragma unroll
      for (int ks=0;ks<4;++ks){
        int ky = 2*ks + (l>>5);
        bfrag a = ld2x8(sp + (oy*4+ky)*84 + ox*4);
        acc = mfma32(a, bw[ks], acc);
      }
      #pragma unroll
      for (int r2=0;r2<16;++r2){
        int row = (r2&3) + 8*(r2>>2) + 4*(l>>5);
        int m = mt*32 + row;
        if (m < 400){
          float v = acc[r2] + bias; v = v>0.f ? v : 0.f;
          *(bf16*)(lw + m*64 + (((l&31)*2) ^ ((m&3)<<4))) = (bf16)v;
        }
      }
    }
  }
  __syncthreads();
  // ---- conv2: wave h handles out cols [32h, 32h+32)
  {
    f32x16 acc2[3];
    #pragma unroll
    for (int a2=0;a2<3;++a2) acc2[a2]=zero16();
    int pb[3];
    #pragma unroll
    for (int mt=0;mt<3;++mt){
      int m = mt*32 + (l&31); int p = m>80 ? 80 : m;
      int oy = p/9, ox = p - oy*9;
      pb[mt] = (oy*2)*20 + ox*2;
    }
    #pragma unroll 4
    for (int ks=0; ks<32; ++ks){
      int k  = ks*16 + 8*(l>>5);
      int ky = k>>7, kx = (k>>5)&3, ci = k&31;
      bfrag b0 = ldg16(w2r + (32*h + (l&31))*512 + k);
      #pragma unroll
      for (int mt=0; mt<3; ++mt){
        int p2 = pb[mt] + ky*20 + kx;
        bfrag a = *(const bfrag*)(lw + p2*64 + ((ci*2) ^ ((p2&3)<<4)));
        acc2[mt] = mfma32(a, b0, acc2[mt]);
      }
    }
    const float bias2 = c2b[32*h + (l&31)];
    #pragma unroll
    for (int mt=0; mt<3; ++mt){
      #pragma unroll
      for (int r2=0;r2<16;++r2){
        int row = (r2&3) + 8*(r2>>2) + 4*(l>>5);
        int m = mt*32 + row;
        if (m < 81){
          float v = acc2[mt][r2] + bias2; v = v>0.f ? v : 0.f;
          act2[(imgbase+img)*5184 + m*64 + 32*h + (l&31)] = (bf16)v;
        }
      }
    }
  }
}

// ---------------------------------------------------------------- conv3 (writes zeros into pad rows)
__global__ __launch_bounds__(256,2) void k_conv3(
    const bf16* __restrict__ act2, const bf16* __restrict__ w3r,
    const float* __restrict__ c3b, bf16* __restrict__ act3)
{
  const int tid=threadIdx.x, w=tid>>6, l=tid&63;
  const long img = (long)blockIdx.x*4 + w;
  const bf16* A = act2 + img*5184;
  f32x16 acc[2][2];
  #pragma unroll
  for(int a2=0;a2<2;++a2){ acc[a2][0]=zero16(); acc[a2][1]=zero16(); }
  #pragma unroll 4
  for (int ks=0; ks<36; ++ks){
    int k  = ks*16 + 8*(l>>5);
    int ky = k/192, rem = k - ky*192, kx = rem>>6, ci = rem&63;
    bfrag b0 = ldg16(w3r + (l&31)*576 + k);
    bfrag b1 = ldg16(w3r + (32+(l&31))*576 + k);
    #pragma unroll
    for (int mt=0; mt<2; ++mt){
      int m = mt*32 + (l&31); int p = m>48 ? 48 : m;
      int oy = p/7, ox = p - oy*7;
      bfrag a = ldg16(A + ((oy+ky)*9 + (ox+kx))*64 + ci);
      acc[mt][0] = mfma32(a, b0, acc[mt][0]);
      acc[mt][1] = mfma32(a, b1, acc[mt][1]);
    }
  }
  const float bias0 = c3b[l&31], bias1 = c3b[32+(l&31)];
  #pragma unroll
  for (int mt=0; mt<2; ++mt){
    #pragma unroll
    for (int r2=0;r2<16;++r2){
      int row = (r2&3) + 8*(r2>>2) + 4*(l>>5);
      int m = mt*32 + row;
      if (m < 50){
        float v0 = 0.f, v1 = 0.f;
        if (m < 49){
          v0 = acc[mt][0][r2] + bias0; v0 = v0>0.f ? v0 : 0.f;
          v1 = acc[mt][1][r2] + bias1; v1 = v1>0.f ? v1 : 0.f;
        }
        act3[img*3200 + m*64 + (l&31)]      = (bf16)v0;
        act3[img*3200 + m*64 + 32 + (l&31)] = (bf16)v1;
      }
    }
  }
}

// ---------------------------------------------------------------- generic GEMM
template<bool RELU, bool OUTBF16>
__global__ __launch_bounds__(256,4) void k_gemm(
    const bf16* __restrict__ A, long lda,
    const bf16* __restrict__ W, long ldb,
    const float* __restrict__ bias,
    float* __restrict__ outF, bf16* __restrict__ outB, long ldo, int K,
    const float* __restrict__ fixR, const int* __restrict__ fixA,
    const float* __restrict__ fixWr, const float* __restrict__ fixWa)
{
  __shared__ bf16 sA[8192];
  char* sb = (char*)sA;
  const int tid=threadIdx.x, w=tid>>6, l=tid&63;
  const int m0 = blockIdx.x*64, n0 = blockIdx.y*128;
  f32x16 acc[2]; acc[0]=zero16(); acc[1]=zero16();
  const int mt = w&1;
  const int rowa = mt*32 + (l&31);
  for (int kc=0; kc<K; kc+=128){
    __syncthreads();
    for (int u = tid; u < 1024; u += 256){
      int row = u>>4, seg = u&15;
      s16x8 v = *(const s16x8*)(A + (long)(m0+row)*lda + kc + seg*8);
      *(s16x8*)(sb + row*256 + ((seg*16) ^ ((row&15)<<4))) = v;
    }
    __syncthreads();
    #pragma unroll
    for (int ks=0; ks<8; ++ks){
      bfrag a = *(const bfrag*)(sb + rowa*256 + ((ks*32 + (l>>5)*16) ^ ((rowa&15)<<4)));
      #pragma unroll
      for (int j=0;j<2;++j){
        int nt = (w>>1)*2 + j;
        bfrag b = ldg16(W + (long)(n0 + nt*32 + (l&31))*ldb + kc + ks*16 + 8*(l>>5));
        acc[j] = mfma32(a, b, acc[j]);
      }
    }
  }
  #pragma unroll
  for (int j=0;j<2;++j){
    int nt = (w>>1)*2 + j;
    int gc = n0 + nt*32 + (l&31);
    float bv = bias ? bias[gc] : 0.f;
    float wrv = fixR ? fixWr[gc] : 0.f;
    #pragma unroll
    for (int r2=0;r2<16;++r2){
      int row = (r2&3) + 8*(r2>>2) + 4*(l>>5);
      long gr = m0 + mt*32 + row;
      float v = acc[j][r2] + bv;
      if (fixR) v += fixR[gr]*wrv + fixWa[(long)fixA[gr]*2048 + gc];
      if (RELU) v = v>0.f ? v : 0.f;
      if (OUTBF16) outB[gr*ldo + gc] = (bf16)v;
      else         outF[gr*ldo + gc] = v;
    }
  }
}

// ---------------------------------------------------------------- LSTM recurrence
// Tag-in-data protocol: h published as f32 with low-7-bit step tag; consumers
// poll the data words directly (one IF round trip). G loads issued before the
// poll so HBM latency hides under the spin.
__global__ __launch_bounds__(256,1) void k_lstm(
    const float* __restrict__ G, const int* __restrict__ done,
    const float* __restrict__ c0, const bf16* __restrict__ Whh,
    uint32_t* __restrict__ hcurT, bf16* __restrict__ hseq,
    float* __restrict__ outH, float* __restrict__ outC)
{
  __shared__ bf16 sh[8192];          // 16 x 512 bf16, swizzled
  __shared__ float sg[4][16][32];
  __shared__ float sc[16][32];
  const int tid=threadIdx.x, w=tid>>6, l=tid&63;
  const int blk=blockIdx.x, grp=blk>>4, jj=blk&15;
  const int bb = grp*16, uu = jj*32;

  for (int p=tid; p<512; p+=256){ int m=p>>5, u=p&31; sc[m][u] = c0[(bb+m)*512 + uu + u]; }

  bfrag wb0[16], wb1[16];
  {
    const long row0 = (long)w*512 + uu + (l&15);
    #pragma unroll
    for (int ks=0; ks<16; ++ks){
      int k = ks*32 + 8*(l>>4);
      wb0[ks] = ldg16(Whh + row0*512 + k);
      wb1[ks] = ldg16(Whh + (row0+16)*512 + k);
    }
  }
  char* shb = (char*)sh;
  const int srow  = tid>>4;          // staging row (batch) 0..15
  const int scol0 = (tid&15)*32;     // staging col base (h elems)

  for (int t=0; t<80; ++t){
    // (a) issue this step's G loads — independent of h, overlap the poll
    float gv0[4], gv1[4];
    {
      const float* Gt = G + ((long)t*64 + bb)*2048 + w*512 + uu;
      #pragma unroll
      for (int r2=0;r2<4;++r2){
        int m2 = (l>>4)*4 + r2;
        gv0[r2] = Gt[(long)m2*2048 + (l&15)];
        gv1[r2] = Gt[(long)m2*2048 + 16 + (l&15)];
      }
    }
    __builtin_amdgcn_sched_barrier(0);
    // (b) poll tagged h words for step t
    {
      const uint32_t* hb = hcurT + (size_t)(t&1)*32768 + (size_t)(bb+srow)*512 + scol0;
      u32x4 hv[8];
      const uint32_t exp = (uint32_t)t;
      for (;;){
        #pragma unroll
        for (int j2=0;j2<8;++j2) hv[j2] = ldcg4(hb + j2*4);
        asm volatile("s_waitcnt vmcnt(0)" ::: "memory");
        bool ok = true;
        #pragma unroll
        for (int j2=0;j2<8;++j2){
          ok &= ((hv[j2][0]&127u)==exp) & ((hv[j2][1]&127u)==exp)
              & ((hv[j2][2]&127u)==exp) & ((hv[j2][3]&127u)==exp);
        }
        if (__all(ok)) break;
      }
      int dn = done[t*64 + bb + srow];
      if (dn){
        #pragma unroll
        for (int j2=0;j2<8;++j2){ u32x4 z = {0,0,0,0}; hv[j2] = z; }
      }
      char* dst = shb + srow*1024;
      #pragma unroll
      for (int c2=0;c2<4;++c2){
        u32x4 outp;
        outp[0] = pkbf(hv[2*c2][0],   hv[2*c2][1]);
        outp[1] = pkbf(hv[2*c2][2],   hv[2*c2][3]);
        outp[2] = pkbf(hv[2*c2+1][0], hv[2*c2+1][1]);
        outp[3] = pkbf(hv[2*c2+1][2], hv[2*c2+1][3]);
        *(u32x4*)(dst + ((scol0*2 + c2*16) ^ (srow<<4))) = outp;
      }
    }
    __syncthreads();
    // (c) h @ Whh^T
    f32x4 a0 = zero4(), a1 = zero4();
    {
      const int row = l&15;
      #pragma unroll
      for (int ks=0; ks<16; ++ks){
        bfrag a = *(const bfrag*)(shb + row*1024 + ((ks*64 + (l>>4)*16) ^ (row<<4)));
        a0 = mfma16(a, wb0[ks], a0);
        a1 = mfma16(a, wb1[ks], a1);
      }
    }
    #pragma unroll
    for (int r2=0;r2<4;++r2){
      int m = (l>>4)*4 + r2;
      sg[w][m][(l&15)]    = a0[r2] + gv0[r2];
      sg[w][m][16+(l&15)] = a1[r2] + gv1[r2];
    }
    __syncthreads();
    // (d) gates + cell + publish tagged h
    {
      int p0 = tid*2; int m = p0>>5, u = p0&31;
      int dn = done[t*64 + bb + m];
      float c_0 = dn ? 0.f : sc[m][u];
      float c_1 = dn ? 0.f : sc[m][u+1];
      float i0=sg[0][m][u],   f0=sg[1][m][u],   g0=sg[2][m][u],   o0=sg[3][m][u];
      float i1=sg[0][m][u+1], f1=sg[1][m][u+1], g1=sg[2][m][u+1], o1=sg[3][m][u+1];
      float cn0 = sigm(f0)*c_0 + sigm(i0)*tanhf(g0);
      float cn1 = sigm(f1)*c_1 + sigm(i1)*tanhf(g1);
      float h_0 = sigm(o0)*tanhf(cn0);
      float h_1 = sigm(o1)*tanhf(cn1);
      sc[m][u] = cn0; sc[m][u+1] = cn1;
      uint32_t tb0 = (__builtin_bit_cast(uint32_t, h_0) & ~127u) | (uint32_t)(t+1);
      uint32_t tb1 = (__builtin_bit_cast(uint32_t, h_1) & ~127u) | (uint32_t)(t+1);
      uint64_t pk64 = (uint64_t)tb0 | ((uint64_t)tb1<<32);
      __hip_atomic_store(
          (uint64_t*)(hcurT + (size_t)((t+1)&1)*32768 + (size_t)(bb+m)*512 + uu + u),
          pk64, __ATOMIC_RELAXED, __HIP_MEMORY_SCOPE_AGENT);
      uint32_t pk = (uint32_t)__builtin_bit_cast(uint16_t,(bf16)h_0)
                  | ((uint32_t)__builtin_bit_cast(uint16_t,(bf16)h_1)<<16);
      *(uint32_t*)(hseq + ((long)t*64 + bb + m)*512 + uu + u) = pk;
      if (t == 79){
        outH[(bb+m)*512 + uu + u]   = h_0;  outH[(bb+m)*512 + uu + u+1] = h_1;
        outC[(bb+m)*512 + uu + u]   = cn0;  outC[(bb+m)*512 + uu + u+1] = cn1;
      }
    }
  }
}

// ---------------------------------------------------------------- fused head2 + dueling combine
// zav[5120,1024] (adv1||val1 relu'd), w2cat[32,1024] (rows 0-17 adv2, 18 val2, rest 0)
__global__ __launch_bounds__(256) void k_qhead(
    const bf16* __restrict__ zav, const bf16* __restrict__ w2cat,
    const float* __restrict__ ab2, const float* __restrict__ vb2,
    float* __restrict__ q)
{
  __shared__ float sq[4][16][32];
  const int tid=threadIdx.x, w=tid>>6, l=tid&63;
  const int s0 = blockIdx.x*64 + w*16;
  f32x4 acc0 = zero4(), acc1 = zero4();
  const int row = l&15;
  #pragma unroll 4
  for (int ks=0; ks<32; ++ks){
    int k = ks*32 + 8*(l>>4);
    bfrag a  = ldg16(zav + (long)(s0+row)*1024 + k);
    bfrag b0 = ldg16(w2cat + (l&15)*1024 + k);
    bfrag b1 = ldg16(w2cat + (16+(l&15))*1024 + k);
    acc0 = mfma16(a, b0, acc0);
    acc1 = mfma16(a, b1, acc1);
  }
  #pragma unroll
  for (int r2=0;r2<4;++r2){
    int m = (l>>4)*4 + r2;
    sq[w][m][l&15]      = acc0[r2];
    sq[w][m][16+(l&15)] = acc1[r2];
  }
  __syncthreads();
  if (l < 16){
    int s = s0 + l;
    float av[18]; float sum = 0.f;
    #pragma unroll
    for (int j=0;j<18;++j){ av[j] = sq[w][l][j] + ab2[j]; sum += av[j]; }
    float val = sq[w][l][18] + vb2[0];
    float mean = sum * (1.f/18.f);
    #pragma unroll
    for (int j=0;j<18;++j) q[(long)s*18 + j] = val + av[j] - mean;
  }
}

// ================================================================ host
extern "C" void kernel_launch(void* const* d_in, const int* in_sizes, int n_in,
                              void* d_out, int out_size, void* d_ws, size_t ws_size,
                              hipStream_t stream)
{
  (void)in_sizes; (void)n_in; (void)out_size;
  const int*   o_in = (const int*)  d_in[0];
  const int*   a_in = (const int*)  d_in[1];
  const float* r_in = (const float*)d_in[2];
  const int*   done = (const int*)  d_in[3];
  const float* h0   = (const float*)d_in[4];
  const float* c0   = (const float*)d_in[5];
  const float* c1w  = (const float*)d_in[6],  *c1b=(const float*)d_in[7];
  const float* c2w  = (const float*)d_in[8],  *c2b=(const float*)d_in[9];
  const float* c3w  = (const float*)d_in[10], *c3b=(const float*)d_in[11];
  const float* fcw  = (const float*)d_in[12], *fcb=(const float*)d_in[13];
  const float* Wih  = (const float*)d_in[14], *WhhF=(const float*)d_in[15];
  const float* bih  = (const float*)d_in[16], *bhh=(const float*)d_in[17];
  const float* aw1  = (const float*)d_in[18], *ab1=(const float*)d_in[19];
  const float* aw2  = (const float*)d_in[20], *ab2=(const float*)d_in[21];
  const float* vw1  = (const float*)d_in[22], *vb1=(const float*)d_in[23];
  const float* vw2  = (const float*)d_in[24], *vb2=(const float*)d_in[25];

  char* ws = (char*)d_ws;
  size_t off = 0;
  auto alloc = [&](size_t b){ size_t p = off; off = (off + b + 255) & ~(size_t)255; return p; };
  bf16*  act2   = (bf16*) (ws + alloc(53084160));   // 5120 x 5184   (G aliases later)
  bf16*  act3   = (bf16*) (ws + alloc(32768000));   // 5120 x 3200   (zav aliases later)
  bf16*  hidden = (bf16*) (ws + alloc(5242880));    // 5120 x 512    (hseq aliases later)
  uint32_t* hcurT = (uint32_t*)(ws + alloc(262144));// 2 x 64 x 512 tagged f32
  bf16*  w1b    = (bf16*) (ws + alloc(4096));
  bf16*  w2r    = (bf16*) (ws + alloc(65536));
  bf16*  w3r    = (bf16*) (ws + alloc(73728));
  bf16*  fcwr   = (bf16*) (ws + alloc(3276800));
  bf16*  Wx     = (bf16*) (ws + alloc(2097152));
  bf16*  Whh    = (bf16*) (ws + alloc(2097152));
  float* biasL  = (float*)(ws + alloc(8192));
  float* Wr     = (float*)(ws + alloc(8192));
  float* Wa     = (float*)(ws + alloc(147456));
  bf16*  headw1 = (bf16*) (ws + alloc(1048576));
  float* headb1 = (float*)(ws + alloc(4096));
  bf16*  w2cat  = (bf16*) (ws + alloc(65536));
  if (off > ws_size) return;

  float* G    = (float*)act2;    // 41.9MB <= 53.1MB
  bf16*  hseq = hidden;
  bf16*  zav  = act3;            // 10.5MB <= 32.8MB

  float* qout = (float*)d_out;
  float* outH = qout + 92160;
  float* outC = qout + 124928;

  k_prep<<<17468, 256, 0, stream>>>(c1w, c2w, c3w, fcw, Wih, WhhF, bih, bhh,
      aw1, aw2, vw1, vw2, h0, w1b, w2r, w3r, fcwr, Wx, Whh,
      biasL, Wr, Wa, headw1, headb1, w2cat, hcurT);
  k_prep2<<<4, 256, 0, stream>>>(ab1, vb1, headb1);

  k_conv12<<<1280, 512, 0, stream>>>(o_in, w1b, c1b, w2r, c2b, act2);
  k_conv3<<<1280, 256, 0, stream>>>(act2, w3r, c3b, act3);
  k_gemm<true,true><<<dim3(80,4), 256, 0, stream>>>(
      act3, 3200, fcwr, 3200, fcb, nullptr, hidden, 512, 3200,
      nullptr, nullptr, nullptr, nullptr);
  k_gemm<false,false><<<dim3(80,16), 256, 0, stream>>>(
      hidden, 512, Wx, 512, biasL, G, nullptr, 2048, 512,
      r_in, a_in, Wr, Wa);

  k_lstm<<<64, 256, 0, stream>>>(G, done, c0, Whh, hcurT, hseq, outH, outC);

  k_gemm<true,true><<<dim3(80,8), 256, 0, stream>>>(
      hseq, 512, headw1, 512, headb1, nullptr, zav, 1024, 512,
      nullptr, nullptr, nullptr, nullptr);
  k_qhead<<<80, 256, 0, stream>>>(zav, w2cat, ab2, vb2, qout);
}